// Round 16
// baseline (194.254 us; speedup 1.0000x reference)
//
#include <hip/hip_runtime.h>

#define HH 192
#define WW 256
#define CCH 2             // channels per chunk (small LDS -> 3 blocks/CU)
#define NCHUNK 32         // 64 / 2
#define THREADS 576       // 9 waves; wave w handles i = w - 4
#define CHSTEP (CCH * HH * WW)
#define ROWF 264          // band row: cols -4..259 (66 x 16B units)
#define CHF  (9 * ROWF)   // 2376 floats per channel (9 band rows)
#define BUFF (CCH * CHF)  // 4752 floats per buffer (19 KiB)
#define NUNITS (CCH * 9 * 66)   // 1188 16B units per chunk

typedef float f4 __attribute__((ext_vector_type(4)));

// async global->LDS, 16B per lane, dest = wave-uniform base + lane*16
#define GLL(gp, lp) __builtin_amdgcn_global_load_lds(                        \
    (const __attribute__((address_space(1))) unsigned int*)(gp),            \
    (__attribute__((address_space(3))) unsigned int*)(lp), 16, 0, 0)

// Established (R14/R15, conflicts==0): block = 1 output row x 256 px,
// wave = i-shift, lane*4 px; wave w reads only band row 8-w so every
// ds_read_b128 is one contiguous 1024B run -> conflict-free.
// R16 attacks the two measured scheduling losses of R15 (159us, occ 25%):
//  1) x1 regs double-buffered: chunk n+1's 2 f4 loads issue at the TOP of
//     chunk n (R15 issued them right before the barrier -> ~900cy naked
//     drain per chunk).
//  2) CCH 4->2: LDS dbuf 76KB -> 38KB -> 3 blocks/CU co-resident; barrier
//     drains now overlap other blocks' compute (block-level TLP, first
//     time this session: occupancy has been pinned at 1 block/CU).
__global__ __launch_bounds__(THREADS) void cost_volume_kernel(
    const float* __restrict__ x1, const float* __restrict__ x2,
    float* __restrict__ out)
{
    __shared__ __align__(16) float smem[2 * BUFF];   // 38016 B

    const int tid  = threadIdx.x;
    const int wave = tid >> 6;      // 0..8 -> i = wave - 4
    const int lane = tid & 63;      // 64 col groups of 4 px

    const int bid = blockIdx.x;
    const int b   = bid & 7;        // batch -> XCD affinity (bid%8 = XCD)
    const int h   = bid >> 3;       // 0..191 output row; h-adjacent blocks
                                    // share 8/9 band rows in the same L2

    // ---- x2 staging: 1188 units = 18 full strips + 36-unit partial ----
    // unit u -> ch=u/594, v=u%594, row=v/66, cu=v%66; col = cu*4-4.
    // LDS float offset = 4u (linear). wave w: strips {w, w+9};
    // wave 0 also takes the partial strip 18 (lanes 0..35).
    auto desc = [&](int s, int& goff) {   // -1 if masked
        const int u = (s << 6) + lane;
        const int ch = u / 594, v = u % 594;
        const int row = v / 66, cu = v % 66;
        const int hg = h + row - 4, wg = (cu << 2) - 4;
        const bool ok = (u < NUNITS) & (cu >= 1) & (cu <= 64) &
                        (hg >= 0) & (hg < HH);
        goff = ok ? (((b * 64 + ch) * HH + hg) * WW + wg) : -1;
    };
    int g0, g1, g2;
    desc(wave,     g0);
    desc(wave + 9, g1);
    desc(18,       g2);
    if (wave != 0) g2 = -1;         // partial strip: wave 0 only

    auto issue = [&](int nb, int n) {
        const int cofs = n * CHSTEP;
        float* const base = smem + nb * BUFF;
        if (g0 >= 0) GLL(x2 + g0 + cofs, base + (wave << 8));
        if (g1 >= 0) GLL(x2 + g1 + cofs, base + ((wave + 9) << 8));
        if (g2 >= 0) GLL(x2 + g2 + cofs, base + (18 << 8));
    };

    // ---- pre-zero LDS (halo/OOB slots persist as zeros) ----
    const f4 z4 = {0.f, 0.f, 0.f, 0.f};
    for (int z = tid; z < 2 * BUFF / 4; z += THREADS) ((f4*)smem)[z] = z4;
    __syncthreads();

    // x1 direct-load base: lane-unique f4, channel 0
    const float* x1base = x1 + ((b * 64) * HH + h) * WW + (lane << 2);

    issue(0, 0);
    // preload x1 chunk 0 (latency covered by the initial barrier drain)
    f4 aC0 = *(const f4*)(x1base);
    f4 aC1 = *(const f4*)(x1base + HH * WW);
    __syncthreads();   // drains vmcnt(0) before s_barrier

    f4 acc0 = z4, acc1 = z4, acc2 = z4, acc3 = z4, acc4 = z4,
       acc5 = z4, acc6 = z4, acc7 = z4, acc8 = z4;

    const int row2 = 8 - wave;      // this wave's band row

    for (int n = 0; n < NCHUNK; ++n) {
        // issue ALL of chunk n+1's memory ops first: GLL + x1 registers.
        // Their latency hides under this chunk's compute; the barrier
        // drain then has little left to wait for.
        f4 aN0 = z4, aN1 = z4;
        if (n + 1 < NCHUNK) {
            issue((n + 1) & 1, n + 1);
            const float* x1c = x1base + (n + 1) * CHSTEP;
            aN0 = *(const f4*)(x1c);
            aN1 = *(const f4*)(x1c + HH * WW);
        }
        const float* sb2 = smem + (n & 1) * BUFF + row2 * ROWF + (lane << 2);

#define CV_CC(CC, AV)                                                        \
        {                                                                    \
            const f4 xv0 = *(const f4*)(sb2 + (CC) * CHF);                   \
            const f4 xv1 = *(const f4*)(sb2 + (CC) * CHF + 4);               \
            const f4 xv2 = *(const f4*)(sb2 + (CC) * CHF + 8);               \
            const f4 w8 = xv0;                                               \
            const f4 w7 = __builtin_shufflevector(xv0, xv1, 1, 2, 3, 4);     \
            const f4 w6 = __builtin_shufflevector(xv0, xv1, 2, 3, 4, 5);     \
            const f4 w5 = __builtin_shufflevector(xv0, xv1, 3, 4, 5, 6);     \
            const f4 w4 = xv1;                                               \
            const f4 w3 = __builtin_shufflevector(xv1, xv2, 1, 2, 3, 4);     \
            const f4 w2 = __builtin_shufflevector(xv1, xv2, 2, 3, 4, 5);     \
            const f4 w1w = __builtin_shufflevector(xv1, xv2, 3, 4, 5, 6);    \
            const f4 w0w = xv2;                                              \
            acc0 = __builtin_elementwise_fma(AV, w0w, acc0);                 \
            acc1 = __builtin_elementwise_fma(AV, w1w, acc1);                 \
            acc2 = __builtin_elementwise_fma(AV, w2, acc2);                  \
            acc3 = __builtin_elementwise_fma(AV, w3, acc3);                  \
            acc4 = __builtin_elementwise_fma(AV, w4, acc4);                  \
            acc5 = __builtin_elementwise_fma(AV, w5, acc5);                  \
            acc6 = __builtin_elementwise_fma(AV, w6, acc6);                  \
            acc7 = __builtin_elementwise_fma(AV, w7, acc7);                  \
            acc8 = __builtin_elementwise_fma(AV, w8, acc8);                  \
        }
        CV_CC(0, aC0)
        CV_CC(1, aC1)
#undef CV_CC

        aC0 = aN0;   // register ping-pong (explicit names, rule #20)
        aC1 = aN1;
        __syncthreads();
    }

    // ---- epilogue ----
    const float scale = 1.0f / 81.0f;
    const int wout = lane << 2;
    // k = (9*i + j) mod 81 = (9*wave + jj + 41) mod 81
#define CV_OUT(JJ)                                                           \
    {                                                                        \
        const int k = (9 * wave + (JJ) + 41) % 81;                           \
        float* po = out + (((long)b * 81 + k) * HH + h) * WW + wout;         \
        *(f4*)po = acc##JJ * scale;                                          \
    }
    CV_OUT(0) CV_OUT(1) CV_OUT(2) CV_OUT(3) CV_OUT(4)
    CV_OUT(5) CV_OUT(6) CV_OUT(7) CV_OUT(8)
#undef CV_OUT
}

extern "C" void kernel_launch(void* const* d_in, const int* in_sizes, int n_in,
                              void* d_out, int out_size, void* d_ws, size_t ws_size,
                              hipStream_t stream) {
    const float* x1 = (const float*)d_in[0];
    const float* x2 = (const float*)d_in[1];
    float* out = (float*)d_out;
    dim3 grid(8 * 192);   // 1536 blocks: batch (XCD-affine) x 192 rows
    dim3 block(THREADS);
    hipLaunchKernelGGL(cost_volume_kernel, grid, block, 0, stream, x1, x2, out);
}

// Round 17
// 119.307 us; speedup vs baseline: 1.6282x; 1.6282x over previous
//
#include <hip/hip_runtime.h>

#define HH 192
#define WW 256
#define CCH 4             // channels per chunk
#define NCHUNK 16         // 64 / 4
#define THREADS 512       // 8 waves (9-wave blocks never co-schedule: R2-R16)
#define CHSTEP (CCH * HH * WW)
#define ROWF 264          // band row: cols -4..259 (66 x 16B units)
#define CHF  (8 * ROWF)   // 2112 floats per channel (8 band rows)
#define BUFF (CCH * CHF)  // 8448 floats per buffer (33.8 KB)
#define NSTRIPS 33        // 2112 units / 64

typedef float f4 __attribute__((ext_vector_type(4)));

// async global->LDS, 16B per lane, dest = wave-uniform base + lane*16
#define GLL(gp, lp) __builtin_amdgcn_global_load_lds(                        \
    (const __attribute__((address_space(1))) unsigned int*)(gp),            \
    (__attribute__((address_space(3))) unsigned int*)(lp), 16, 0, 0)

// Session-established facts this kernel is built on:
//  * ds_read_b128 is conflict-FREE iff the wave's 64 lanes read one
//    contiguous 1024B run (R12/R14 measured 0; all row-split layouts pay
//    ~4cyc: R8/R11/R13). Here every read has wave-uniform row -> 0.
//  * 576-thread (9-wave) blocks never co-schedule (occupancy pinned ~25%
//    at ANY LDS 28-81KB); 512-thread blocks reached 41% (R12). So: 8-wave
//    blocks; the 9th i-shift becomes mode-B blocks.
//  * barrier vmcnt(0) drains are the residual cost (R14-16); 2 blocks/CU
//    co-residency (67.6KB LDS, VGPR<=128) overlaps them with compute.
// Mode A (bid<1536): 1 output row, wave w = i-4..3, lane*4 px.
// Mode B (bid>=1536): 8 output rows, wave = row, i=+4 only (k=32..40).
__global__ __launch_bounds__(THREADS) void cost_volume_kernel(
    const float* __restrict__ x1, const float* __restrict__ x2,
    float* __restrict__ out)
{
    __shared__ __align__(16) float smem[2 * BUFF];   // 67584 B

    const int tid  = threadIdx.x;
    const int wave = tid >> 6;      // 0..7
    const int lane = tid & 63;      // 64 col groups of 4 px

    const int bid = blockIdx.x;
    const bool isB = (bid >= 1536);
    int b, hout, hbase, drow;
    if (!isB) {                     // mode A: wave w -> i = w - 4
        b     = bid & 7;            // batch -> XCD affinity
        hout  = bid >> 3;           // output row 0..191
        hbase = hout - 3;           // band[d] = hout + d - 3, d in 0..7
        drow  = 7 - wave;           // band row with x2[hout - i]
    } else {                        // mode B: i = +4, wave = row
        const int t = bid - 1536;   // 0..191
        b     = t & 7;
        const int h0 = (t >> 3) << 3;
        hout  = h0 + wave;
        hbase = h0 - 4;             // band[d] = h0 + d - 4
        drow  = wave;               // x2 row = hout - 4 = band[wave]
    }

    // ---- x2 staging: [4 ch][8 rows][66 units] = 2112 units = 33 strips ----
    // unit u -> ch=u/528, v=u%528, d=v/66, cu=v%66; col = cu*4-4.
    // LDS float offset = 4u (linear). wave w: strips {w,w+8,w+16,w+24};
    // wave 0 also takes strip 32.
    auto desc = [&](int s, int& goff) {   // -1 if masked
        const int u = (s << 6) + lane;
        const int ch = u / 528, v = u % 528;
        const int d = v / 66, cu = v % 66;
        const int hg = hbase + d, wg = (cu << 2) - 4;
        const bool ok = (cu >= 1) & (cu <= 64) & (hg >= 0) & (hg < HH);
        goff = ok ? (((b * 64 + ch) * HH + hg) * WW + wg) : -1;
    };
    int g0, g1, g2, g3, g4;
    desc(wave,      g0);
    desc(wave + 8,  g1);
    desc(wave + 16, g2);
    desc(wave + 24, g3);
    desc(32,        g4);
    if (wave != 0) g4 = -1;         // strip 32: wave 0 only

    auto issue = [&](int nb, int n) {
        const int cofs = n * CHSTEP;
        float* const base = smem + nb * BUFF;
        if (g0 >= 0) GLL(x2 + g0 + cofs, base + (wave << 8));
        if (g1 >= 0) GLL(x2 + g1 + cofs, base + ((wave + 8) << 8));
        if (g2 >= 0) GLL(x2 + g2 + cofs, base + ((wave + 16) << 8));
        if (g3 >= 0) GLL(x2 + g3 + cofs, base + ((wave + 24) << 8));
        if (g4 >= 0) GLL(x2 + g4 + cofs, base + (32 << 8));
    };

    // ---- pre-zero LDS (halo/OOB slots persist as zeros) ----
    const f4 z4 = {0.f, 0.f, 0.f, 0.f};
    for (int z = tid; z < 2 * BUFF / 4; z += THREADS) ((f4*)smem)[z] = z4;
    __syncthreads();

    // x1 direct-load base: this thread's 4 px of its output row, channel 0.
    // Mode A: all 8 waves load the same row (L1 broadcast); mode B: unique.
    const float* x1base = x1 + ((b * 64) * HH + hout) * WW + (lane << 2);

    issue(0, 0);
    f4 aC0 = *(const f4*)(x1base);
    f4 aC1 = *(const f4*)(x1base + HH * WW);
    f4 aC2 = *(const f4*)(x1base + 2 * HH * WW);
    f4 aC3 = *(const f4*)(x1base + 3 * HH * WW);
    __syncthreads();   // drains vmcnt(0) before s_barrier

    f4 acc0 = z4, acc1 = z4, acc2 = z4, acc3 = z4, acc4 = z4,
       acc5 = z4, acc6 = z4, acc7 = z4, acc8 = z4;

    for (int n = 0; n < NCHUNK; ++n) {
        // issue ALL of chunk n+1's memory ops first (GLL + x1 regs); their
        // latency hides under this chunk's compute (~2000cy > ~900cy HBM).
        f4 aN0 = z4, aN1 = z4, aN2 = z4, aN3 = z4;
        if (n + 1 < NCHUNK) {
            issue((n + 1) & 1, n + 1);
            const float* x1c = x1base + (n + 1) * CHSTEP;
            aN0 = *(const f4*)(x1c);
            aN1 = *(const f4*)(x1c + HH * WW);
            aN2 = *(const f4*)(x1c + 2 * HH * WW);
            aN3 = *(const f4*)(x1c + 3 * HH * WW);
        }
        // all reads: wave-uniform row -> one contiguous 1024B run -> 0 conflicts
        const float* sb2 = smem + (n & 1) * BUFF + drow * ROWF + (lane << 2);

#define CV_CC(CC, AV)                                                        \
        {                                                                    \
            const f4 xv0 = *(const f4*)(sb2 + (CC) * CHF);                   \
            const f4 xv1 = *(const f4*)(sb2 + (CC) * CHF + 4);               \
            const f4 xv2 = *(const f4*)(sb2 + (CC) * CHF + 8);               \
            const f4 w8 = xv0;                                               \
            const f4 w7 = __builtin_shufflevector(xv0, xv1, 1, 2, 3, 4);     \
            const f4 w6 = __builtin_shufflevector(xv0, xv1, 2, 3, 4, 5);     \
            const f4 w5 = __builtin_shufflevector(xv0, xv1, 3, 4, 5, 6);     \
            const f4 w4 = xv1;                                               \
            const f4 w3 = __builtin_shufflevector(xv1, xv2, 1, 2, 3, 4);     \
            const f4 w2 = __builtin_shufflevector(xv1, xv2, 2, 3, 4, 5);     \
            const f4 w1w = __builtin_shufflevector(xv1, xv2, 3, 4, 5, 6);    \
            const f4 w0w = xv2;                                              \
            acc0 = __builtin_elementwise_fma(AV, w0w, acc0);                 \
            acc1 = __builtin_elementwise_fma(AV, w1w, acc1);                 \
            acc2 = __builtin_elementwise_fma(AV, w2, acc2);                  \
            acc3 = __builtin_elementwise_fma(AV, w3, acc3);                  \
            acc4 = __builtin_elementwise_fma(AV, w4, acc4);                  \
            acc5 = __builtin_elementwise_fma(AV, w5, acc5);                  \
            acc6 = __builtin_elementwise_fma(AV, w6, acc6);                  \
            acc7 = __builtin_elementwise_fma(AV, w7, acc7);                  \
            acc8 = __builtin_elementwise_fma(AV, w8, acc8);                  \
        }
        CV_CC(0, aC0)
        CV_CC(1, aC1)
        CV_CC(2, aC2)
        CV_CC(3, aC3)
#undef CV_CC

        aC0 = aN0;   // register ping-pong (explicit names, rule #20)
        aC1 = aN1;
        aC2 = aN2;
        aC3 = aN3;
        __syncthreads();
    }

    // ---- epilogue ----
    const float scale = 1.0f / 81.0f;
    const int wout = lane << 2;
    // mode A: k = (9*i + j) mod 81 = (9*wave + jj + 41) mod 81
    // mode B: i=+4 -> k = (36 + jj - 4) mod 81 = 32 + jj
#define CV_OUT(JJ)                                                           \
    {                                                                        \
        const int k = isB ? (32 + (JJ)) : (9 * wave + (JJ) + 41) % 81;       \
        float* po = out + (((long)b * 81 + k) * HH + hout) * WW + wout;      \
        *(f4*)po = acc##JJ * scale;                                          \
    }
    CV_OUT(0) CV_OUT(1) CV_OUT(2) CV_OUT(3) CV_OUT(4)
    CV_OUT(5) CV_OUT(6) CV_OUT(7) CV_OUT(8)
#undef CV_OUT
}

extern "C" void kernel_launch(void* const* d_in, const int* in_sizes, int n_in,
                              void* d_out, int out_size, void* d_ws, size_t ws_size,
                              hipStream_t stream) {
    const float* x1 = (const float*)d_in[0];
    const float* x2 = (const float*)d_in[1];
    float* out = (float*)d_out;
    // 1536 mode-A blocks (batch&7 x 192 rows, i=-4..3 per wave)
    // + 192 mode-B blocks (batch&7 x 24 row-octets, i=+4)
    dim3 grid(1536 + 192);
    dim3 block(THREADS);
    hipLaunchKernelGGL(cost_volume_kernel, grid, block, 0, stream, x1, x2, out);
}